// Round 10
// baseline (90.931 us; speedup 1.0000x reference)
//
#include <hip/hip_runtime.h>
#include <cstdint>
#include <cstddef>

#define HW    4096
#define IMG   64
#define DIMC  192
#define NH    4
#define CH    48
#define CPAD  64
#define KVSPLIT 8
#define NTILE (HW / 64 / KVSPLIT)
#define LOG2E 1.4426950408889634f

typedef __bf16 bf16x8 __attribute__((ext_vector_type(8)));
typedef float  f32x4  __attribute__((ext_vector_type(4)));
typedef float  f32x16 __attribute__((ext_vector_type(16)));
typedef unsigned short u16x8 __attribute__((ext_vector_type(8)));
typedef unsigned int   u32x4 __attribute__((ext_vector_type(4)));

#if __has_builtin(__builtin_amdgcn_exp2f)
#define EXP2(x) __builtin_amdgcn_exp2f(x)
#else
#define EXP2(x) exp2f(x)
#endif

__device__ __forceinline__ unsigned short f2bf(float f) {
  unsigned int u = __builtin_bit_cast(unsigned int, f);
  u = (u + 0x7FFFu + ((u >> 16) & 1u)) >> 16;   // RNE
  return (unsigned short)u;
}
__device__ __forceinline__ float bf2f(unsigned short u) {
  return __builtin_bit_cast(float, (unsigned int)u << 16);
}
__device__ __forceinline__ f32x4 mfma16(bf16x8 a, bf16x8 b, f32x4 c) {
  return __builtin_amdgcn_mfma_f32_16x16x32_bf16(a, b, c, 0, 0, 0);
}
__device__ __forceinline__ f32x16 mfma32(bf16x8 a, bf16x8 b, f32x16 c) {
  return __builtin_amdgcn_mfma_f32_32x32x16_bf16(a, b, c, 0, 0, 0);
}
__device__ __forceinline__ void gl16(const void* g, void* l) {
  __builtin_amdgcn_global_load_lds(
      (const __attribute__((address_space(1))) unsigned int*)g,
      (__attribute__((address_space(3))) unsigned int*)l, 16, 0, 0);
}
__device__ __forceinline__ unsigned int cvtpk(float lo, float hi) {
  unsigned int d;
  asm("v_cvt_pk_bf16_f32 %0, %1, %2" : "=v"(d) : "v"(lo), "v"(hi));
  return d;
}
__device__ __forceinline__ void swap32(unsigned int& a, unsigned int& b) {
  asm("v_permlane32_swap_b32 %0, %1" : "+v"(a), "+v"(b));
}

// ---------------------------------------------------------------------------
// P0: pack to chunk-major bf16.
// ---------------------------------------------------------------------------
__global__ __launch_bounds__(256) void pack3_kernel(
    const float* __restrict__ x, const float* __restrict__ qkv_w,
    const float* __restrict__ proj_w, unsigned short* __restrict__ xb,
    unsigned short* __restrict__ wqkv, unsigned short* __restrict__ wproj) {
  const int bx = blockIdx.x, tid = threadIdx.x;
  if (bx < 128) {
    const int it = bx * 256 + tid;        // 0..32767
    const int b = it >> 14;
    const int q4 = (it >> 12) & 3;
    const int p = it & 4095;
    const int c0 = q4 * 48;
    const float* src = x + ((size_t)b * DIMC + c0) * HW + p;
    float v[48];
    #pragma unroll
    for (int j = 0; j < 48; ++j) v[j] = src[(size_t)j * HW];
    #pragma unroll
    for (int g = 0; g < 6; ++g) {
      const int ch = c0 + g * 8;
      const int kc = ch >> 5, off = ch & 31;
      u16x8 gg;
      #pragma unroll
      for (int j = 0; j < 8; ++j) gg[j] = f2bf(v[g * 8 + j]);
      *(u16x8*)(xb + (((size_t)b * 6 + kc) * HW + p) * 32 + off) = gg;
    }
  } else {
    const int row = (bx - 128) * 256 + tid;     // 0..767
    if (row < 576) {
      const float* src = qkv_w + (size_t)row * DIMC;
      #pragma unroll
      for (int kc = 0; kc < 6; ++kc) {
        u16x8 g0, g1, g2, g3;
        #pragma unroll
        for (int j = 0; j < 8; ++j) {
          g0[j] = f2bf(src[kc * 32 + j]);      g1[j] = f2bf(src[kc * 32 + 8 + j]);
          g2[j] = f2bf(src[kc * 32 + 16 + j]); g3[j] = f2bf(src[kc * 32 + 24 + j]);
        }
        unsigned short* dst = wqkv + ((size_t)kc * 576 + row) * 32;
        *(u16x8*)dst = g0; *(u16x8*)(dst + 8) = g1;
        *(u16x8*)(dst + 16) = g2; *(u16x8*)(dst + 24) = g3;
      }
    } else {
      const int oc = row - 576;                // 0..191
      const float* src = proj_w + (size_t)oc * DIMC;
      #pragma unroll
      for (int kc = 0; kc < 6; ++kc) {
        u16x8 g0, g1, g2, g3;
        #pragma unroll
        for (int j = 0; j < 8; ++j) {
          g0[j] = f2bf(src[kc * 32 + j]);      g1[j] = f2bf(src[kc * 32 + 8 + j]);
          g2[j] = f2bf(src[kc * 32 + 16 + j]); g3[j] = f2bf(src[kc * 32 + 24 + j]);
        }
        unsigned short* dst = wproj + ((size_t)kc * DIMC + oc) * 32;
        *(u16x8*)dst = g0; *(u16x8*)(dst + 8) = g1;
        *(u16x8*)(dst + 16) = g2; *(u16x8*)(dst + 24) = g3;
      }
    }
  }
}

// ---------------------------------------------------------------------------
// G1: qkv GEMM, 192-oc blocks (3 sequential subtiles/wave). Grid (3, 64, 2).
// ---------------------------------------------------------------------------
__global__ __launch_bounds__(256) void qkv_gemm_kernel(
    const unsigned short* __restrict__ xb, const unsigned short* __restrict__ wb,
    unsigned short* __restrict__ Cout) {
  const int tid = threadIdx.x;
  const int lane = tid & 63, wv = tid >> 6;
  const int l15 = lane & 15, l4 = lane >> 4;
  const int ocbase = blockIdx.x * 192;
  const int px0 = blockIdx.y * 64;
  const int b   = blockIdx.z;

  f32x4 acc[3][4];
  #pragma unroll
  for (int s = 0; s < 3; ++s)
    #pragma unroll
    for (int p = 0; p < 4; ++p) acc[s][p] = f32x4{0.f, 0.f, 0.f, 0.f};

  #pragma unroll
  for (int kc = 0; kc < 6; ++kc) {
    const unsigned short* xrow = xb + (((size_t)b * 6 + kc) * HW + px0 + l15) * 32 + l4 * 8;
    bf16x8 Bf[4];
    #pragma unroll
    for (int p = 0; p < 4; ++p) Bf[p] = *(const bf16x8*)(xrow + p * 512);
    #pragma unroll
    for (int s = 0; s < 3; ++s) {
      const int oc = ocbase + s * 64 + wv * 16 + l15;
      const bf16x8 af = *(const bf16x8*)(wb + ((size_t)kc * 576 + oc) * 32 + l4 * 8);
      #pragma unroll
      for (int p = 0; p < 4; ++p) acc[s][p] = mfma16(af, Bf[p], acc[s][p]);
    }
  }
  #pragma unroll
  for (int s = 0; s < 3; ++s) {
    unsigned short* Cb = Cout + ((size_t)b * 576 + ocbase + s * 64 + wv * 16) * HW + px0;
    #pragma unroll
    for (int p = 0; p < 4; ++p)
      #pragma unroll
      for (int r = 0; r < 4; ++r)
        Cb[(size_t)(l4 * 4 + r) * HW + p * 16 + l15] = f2bf(acc[s][p][r]);
  }
}

// ---------------------------------------------------------------------------
// K2: depthwise 3x3, bf16 in/out, fp32 LDS tile + rolling registers.
// ---------------------------------------------------------------------------
__global__ __launch_bounds__(256) void dw_conv3_kernel(
    const unsigned short* __restrict__ X, const float* __restrict__ W,
    unsigned short* __restrict__ Y) {
  __shared__ float T[66][72];
  const int bc = blockIdx.x;            // b*576 + ch
  const int ch = bc % 576;
  const int tid = threadIdx.x;
  const unsigned short* Xb = X + (size_t)bc * HW;
  #pragma unroll
  for (int i = 0; i < 4; ++i) {
    const int idx = i * 256 + tid;      // quads
    const int row = idx >> 4, c4 = (idx & 15) << 2;
    const ushort4 u = *(const ushort4*)(Xb + row * 64 + c4);
    float4 f; f.x = bf2f(u.x); f.y = bf2f(u.y); f.z = bf2f(u.z); f.w = bf2f(u.w);
    *(float4*)&T[row + 1][c4 + 4] = f;
  }
  if (tid < 72) { T[0][tid] = 0.f; T[65][tid] = 0.f; }
  if (tid >= 128 && tid < 194) { const int r = tid - 128; T[r][3] = 0.f; T[r][68] = 0.f; }
  float w[9];
  #pragma unroll
  for (int i = 0; i < 9; ++i) w[i] = W[ch * 9 + i];
  __syncthreads();

  const int xx = tid & 63, ys = (tid >> 6) << 4;
  const int c = xx + 4;
  float a0 = T[ys][c - 1],     a1 = T[ys][c],     a2 = T[ys][c + 1];
  float b0 = T[ys + 1][c - 1], b1 = T[ys + 1][c], b2 = T[ys + 1][c + 1];
  unsigned short* Yb = Y + (size_t)bc * HW;
  #pragma unroll
  for (int k = 0; k < 16; ++k) {
    const float c0 = T[ys + k + 2][c - 1], c1 = T[ys + k + 2][c], c2 = T[ys + k + 2][c + 1];
    const float s = w[0] * a0 + w[1] * a1 + w[2] * a2
                  + w[3] * b0 + w[4] * b1 + w[5] * b2
                  + w[6] * c0 + w[7] * c1 + w[8] * c2;
    Yb[(ys + k) * 64 + xx] = f2bf(s);
    a0 = b0; a1 = b1; a2 = b2; b0 = c0; b1 = c1; b2 = c2;
  }
}

// ---------------------------------------------------------------------------
// K3: l2norm + temp*log2e + pack (bf16 input), split by q/k/v section.
// ---------------------------------------------------------------------------
__global__ __launch_bounds__(256) void norm_pack3_kernel(
    const unsigned short* __restrict__ Dw, const float* __restrict__ temp,
    unsigned short* __restrict__ Qr, unsigned short* __restrict__ Kr,
    unsigned short* __restrict__ Vs) {
  const int px = blockIdx.x * 256 + threadIdx.x;
  const int sel = blockIdx.y >> 2, h = blockIdx.y & 3;
  const int b = blockIdx.z;
  const int bh = b * NH + h;
  const unsigned short* base = Dw + ((size_t)b * 576 + sel * DIMC + h * CH) * HW + px;

  float v[CH];
  if (sel == 2) {  // V: no norm
    const int kt = px & ~63, kl = px & 63;
    #pragma unroll
    for (int c = 0; c < CH; ++c)
      Vs[((size_t)bh * CH + c) * HW + kt + (kl ^ ((c & 7) << 3))] = base[(size_t)c * HW];
    return;
  }
  float ss = 0.f;
  #pragma unroll
  for (int j = 0; j < CH; ++j) { v[j] = bf2f(base[(size_t)j * HW]); ss += v[j] * v[j]; }
  const u16x8 zz = {0, 0, 0, 0, 0, 0, 0, 0};
  if (sel == 0) {  // Q: fold temperature*log2e
    const float sc = temp[h] * LOG2E / fmaxf(sqrtf(ss), 1e-12f);
    u16x8 gr[8];
    #pragma unroll
    for (int g = 0; g < 6; ++g)
      #pragma unroll
      for (int j = 0; j < 8; ++j) gr[g][j] = f2bf(v[g * 8 + j] * sc);
    gr[6] = zz; gr[7] = zz;
    unsigned short* qrow = Qr + ((size_t)bh * HW + px) * CPAD;
    #pragma unroll
    for (int g = 0; g < 8; ++g) *(u16x8*)(qrow + g * 8) = gr[g];
  } else {         // K: swizzled granules
    const int ksw = (px & 3) | (((px >> 3) & 1) << 2);
    const float sc = 1.0f / fmaxf(sqrtf(ss), 1e-12f);
    u16x8 gr[8];
    #pragma unroll
    for (int g = 0; g < 6; ++g)
      #pragma unroll
      for (int j = 0; j < 8; ++j) gr[g][j] = f2bf(v[g * 8 + j] * sc);
    gr[6] = zz; gr[7] = zz;
    unsigned short* krow = Kr + ((size_t)bh * HW + px) * CPAD;
    #pragma unroll
    for (int g = 0; g < 8; ++g) *(u16x8*)(krow + (g ^ ksw) * 8) = gr[g];
  }
}

// ---------------------------------------------------------------------------
// K4: flash attention v9 — sequential-kb register diet (S live = 32 VGPR)
// to fit __launch_bounds__(256,3) => 3 waves/SIMD; KVSPLIT=8 => 1024 blocks
// fills 3 blocks/CU. Static-max softmax, MFMA ones-channel row-sum,
// cvt_pk+permlane32 P-path all unchanged.
// ---------------------------------------------------------------------------
__global__ __launch_bounds__(256, 3) void flash9_kernel(
    const unsigned short* __restrict__ Qr,
    const unsigned short* __restrict__ Kr,
    const unsigned short* __restrict__ Vs,
    const float* __restrict__ temp,
    unsigned short* __restrict__ Opart, float* __restrict__ Lpart) {
  __shared__ __align__(16) union {
    struct { unsigned short Kl[2][4096]; unsigned short Vl[2][4096]; } s;
    float T[256][53];
  } lds;
  const int tid = threadIdx.x;
  const int lane = tid & 63, wv = tid >> 6;
  const int l31 = lane & 31, lhi = lane >> 5;
  const int bh = blockIdx.x, qt = blockIdx.y, sp = blockIdx.z;
  const int qb = qt * 256 + wv * 64;
  const float m = fabsf(temp[bh & 3]) * LOG2E * 1.05f + 0.1f;

  for (int i = tid; i < 1024; i += 256) {
    const unsigned short vv = (i < 64) ? (unsigned short)0x3F80 : (unsigned short)0;
    lds.s.Vl[0][3072 + i] = vv;
    lds.s.Vl[1][3072 + i] = vv;
  }

  const unsigned short* Qb = Qr + ((size_t)bh * HW + qb) * CPAD;
  bf16x8 qf[2][3];
  #pragma unroll
  for (int qb2 = 0; qb2 < 2; ++qb2)
    #pragma unroll
    for (int ci = 0; ci < 3; ++ci)
      qf[qb2][ci] = *(const bf16x8*)(Qb + (size_t)(qb2 * 32 + l31) * CPAD + ci * 16 + lhi * 8);

  const char* kg = (const char*)Kr + ((size_t)bh * HW + (size_t)sp * (HW / KVSPLIT)) * 128;
  const char* vg = (const char*)Vs + (size_t)bh * CH * HW * 2 + (size_t)sp * (HW / KVSPLIT) * 2;
  const int koA = tid * 16;
  const int vgA = (tid >> 3) * 8192 + (tid & 7) * 16;
  const int vgB = (32 + (tid >> 3)) * 8192 + (tid & 7) * 16;

  auto stage = [&](int buf, const char* kp, const char* vp) {
    char* kl = (char*)&lds.s.Kl[buf][0];
    gl16(kp + koA,        kl + koA);
    gl16(kp + 4096 + koA, kl + 4096 + koA);
    char* vl = (char*)&lds.s.Vl[buf][0];
    gl16(vp + vgA, vl + tid * 16);
    if (tid < 128) gl16(vp + vgB, vl + 4096 + tid * 16);
  };

  f32x16 o[2][2];
  #pragma unroll
  for (int cb = 0; cb < 2; ++cb)
    #pragma unroll
    for (int qb2 = 0; qb2 < 2; ++qb2)
      #pragma unroll
      for (int i = 0; i < 16; ++i) o[cb][qb2][i] = 0.f;

  stage(0, kg, vg);
  kg += 8192; vg += 128;
  __syncthreads();
  int cur = 0;
  for (int t = 0; t < NTILE; ++t) {
    if (t + 1 < NTILE) { stage(cur ^ 1, kg, vg); kg += 8192; vg += 128; }
    const unsigned short* KL = &lds.s.Kl[cur][0];
    const unsigned short* VL = &lds.s.Vl[cur][0];

    // ---- sequential kb: S(kb) -> exp2 -> PV(kb); only one S[2] live ----
    #pragma unroll
    for (int kb = 0; kb < 2; ++kb) {
      const int krow = kb * 32 + l31;
      const int ksw = (krow & 3) | (((krow >> 3) & 1) << 2);
      bf16x8 kf[3];
      #pragma unroll
      for (int ci = 0; ci < 3; ++ci)
        kf[ci] = *(const bf16x8*)(KL + krow * 64 + (((ci * 2 + lhi) ^ ksw) * 8));
      f32x16 S[2];
      __builtin_amdgcn_s_setprio(1);
      #pragma unroll
      for (int qb2 = 0; qb2 < 2; ++qb2) {
        f32x16 acc;
        #pragma unroll
        for (int i = 0; i < 16; ++i) acc[i] = -m;
        #pragma unroll
        for (int ci = 0; ci < 3; ++ci) acc = mfma32(kf[ci], qf[qb2][ci], acc);
        S[qb2] = acc;
      }
      __builtin_amdgcn_s_setprio(0);

      #pragma unroll
      for (int qb2 = 0; qb2 < 2; ++qb2)
        #pragma unroll
        for (int i = 0; i < 16; ++i) S[qb2][i] = EXP2(S[qb2][i]);

      #pragma unroll
      for (int kh = 0; kh < 2; ++kh) {            // kc = kb*2 + kh
        const int kc = kb * 2 + kh, rb = kh * 8;
        bf16x8 pb[2];
        #pragma unroll
        for (int qb2 = 0; qb2 < 2; ++qb2) {
          unsigned int w0 = cvtpk(S[qb2][rb + 0], S[qb2][rb + 1]);
          unsigned int w1 = cvtpk(S[qb2][rb + 2], S[qb2][rb + 3]);
          unsigned int w2 = cvtpk(S[qb2][rb + 4], S[qb2][rb + 5]);
          unsigned int w3 = cvtpk(S[qb2][rb + 6], S[qb2][rb + 7]);
          swap32(w0, w2);
          swap32(w1, w3);
          u32x4 ww = {w0, w1, w2, w3};
          pb[qb2] = __builtin_bit_cast(bf16x8, ww);
        }
        __builtin_amdgcn_s_setprio(1);
        #pragma unroll
        for (int cb = 0; cb < 2; ++cb) {
          const int crow = cb * 32 + l31;
          const bf16x8 vf = *(const bf16x8*)(VL + crow * 64 + (((kc * 2 + lhi) ^ (crow & 7)) * 8));
          #pragma unroll
          for (int qb2 = 0; qb2 < 2; ++qb2) o[cb][qb2] = mfma32(vf, pb[qb2], o[cb][qb2]);
        }
        __builtin_amdgcn_s_setprio(0);
      }
    }
    __syncthreads();
    cur ^= 1;
  }

  // ---- epilogue: transpose O via LDS -> Opart[q][48] bf16 + Lpart ----
  #pragma unroll
  for (int cb = 0; cb < 2; ++cb)
    #pragma unroll
    for (int qb2 = 0; qb2 < 2; ++qb2) {
      const int ql = wv * 64 + qb2 * 32 + l31;
      #pragma unroll
      for (int r = 0; r < 16; ++r) {
        const int c = cb * 32 + (r & 3) + 8 * (r >> 2) + 4 * lhi;
        if (c < 48) lds.T[ql][c] = o[cb][qb2][r];
      }
      if (lhi == 0) lds.T[ql][48] = o[1][qb2][8];
    }
  __syncthreads();
  {
    const int ql = tid;
    const int qg = qt * 256 + ql;
    float vv[48];
    #pragma unroll
    for (int c = 0; c < 48; ++c) vv[c] = lds.T[ql][c];
    const float Lv = lds.T[ql][48];
    unsigned short* Ob = Opart + ((size_t)(sp * 8 + bh) * HW + qg) * 48;
    #pragma unroll
    for (int g = 0; g < 6; ++g) {
      u16x8 gg;
      #pragma unroll
      for (int j = 0; j < 8; ++j) gg[j] = f2bf(vv[g * 8 + j]);
      *(u16x8*)(Ob + g * 8) = gg;
    }
    Lpart[(size_t)(sp * 8 + bh) * HW + qg] = Lv;
  }
}

// ---------------------------------------------------------------------------
// G2: proj GEMM with fused split-combine (8 splits), px-tile 16,
// grid (1,256,2) = 512 blocks.
// ---------------------------------------------------------------------------
__global__ __launch_bounds__(256) void proj_gemm_kernel(
    const unsigned short* __restrict__ Opart, const float* __restrict__ Lpart,
    const unsigned short* __restrict__ wb, float* __restrict__ Cout) {
  const int tid = threadIdx.x;
  const int lane = tid & 63, wv = tid >> 6;
  const int l15 = lane & 15, l4 = lane >> 4;
  const int px0 = blockIdx.y * 16;
  const int b   = blockIdx.z;

  bf16x8 Bf[6];
  #pragma unroll
  for (int kc = 0; kc < 6; ++kc) {
    const int ch0 = kc * 32 + l4 * 8;
    const int head = ch0 / 48, off = ch0 % 48;
    const int px = px0 + l15;
    float ls = 0.f;
    #pragma unroll
    for (int sp = 0; sp < KVSPLIT; ++sp)
      ls += Lpart[(size_t)(sp * 8 + b * 4 + head) * HW + px];
    const float inv = 1.f / ls;
    float a8[8] = {};
    #pragma unroll
    for (int sp = 0; sp < KVSPLIT; ++sp) {
      const u16x8 u = *(const u16x8*)(Opart +
          ((size_t)(sp * 8 + b * 4 + head) * HW + px) * 48 + off);
      #pragma unroll
      for (int j = 0; j < 8; ++j) a8[j] += bf2f(u[j]);
    }
    u16x8 g;
    #pragma unroll
    for (int j = 0; j < 8; ++j) g[j] = f2bf(a8[j] * inv);
    Bf[kc] = __builtin_bit_cast(bf16x8, g);
  }
  #pragma unroll
  for (int s = 0; s < 3; ++s) {
    const int oc = s * 64 + wv * 16 + l15;
    f32x4 acc = {0.f, 0.f, 0.f, 0.f};
    #pragma unroll
    for (int kc = 0; kc < 6; ++kc) {
      const bf16x8 af = *(const bf16x8*)(wb + ((size_t)kc * DIMC + oc) * 32 + l4 * 8);
      acc = mfma16(af, Bf[kc], acc);
    }
    float* Cb = Cout + ((size_t)b * DIMC + s * 64 + wv * 16) * HW + px0;
    #pragma unroll
    for (int r = 0; r < 4; ++r)
      Cb[(size_t)(l4 * 4 + r) * HW + l15] = acc[r];
  }
}

// ---------------------------------------------------------------------------
extern "C" void kernel_launch(void* const* d_in, const int* in_sizes, int n_in,
                              void* d_out, int out_size, void* d_ws, size_t ws_size,
                              hipStream_t stream) {
  const float* x      = (const float*)d_in[0];
  const float* qkv_w  = (const float*)d_in[1];
  const float* dw_w   = (const float*)d_in[2];
  const float* proj_w = (const float*)d_in[3];
  const float* temp   = (const float*)d_in[4];

  char* ws = (char*)d_ws;
  // layout (lifetime-ordered so Opart can overlay dead conv buffers):
  unsigned short* wqkv  = (unsigned short*)(ws);              //       0 +   221,184
  unsigned short* wproj = (unsigned short*)(ws + 221184);     //         +    73,728
  unsigned short* Qr    = (unsigned short*)(ws + 294912);     //         + 4,194,304
  unsigned short* Kr    = (unsigned short*)(ws + 4489216);    //         + 4,194,304
  unsigned short* Vs    = (unsigned short*)(ws + 8683520);    //         + 3,145,728
  unsigned short* xb    = (unsigned short*)(ws + 11829248);   //         + 3,145,728
  unsigned short* qkvb  = (unsigned short*)(ws + 14974976);   //         + 9,437,184
  unsigned short* dwb   = (unsigned short*)(ws + 24412160);   //         + 9,437,184 (ends 33,849,344)
  // Opart overlays xb/qkvb/dwb (all dead before flash writes):
  unsigned short* Opart = (unsigned short*)(ws + 11829248);   // [sp=8][bh][q][48] = 25,165,824
  float*          Lpart = (float*)(ws + 36995072);            //         + 1,048,576

  // 0) pack x + weights to chunk-major bf16
  pack3_kernel<<<dim3(131), 256, 0, stream>>>(x, qkv_w, proj_w, xb, wqkv, wproj);
  // 1) qkv 1x1 conv (bf16 MFMA GEMM, bf16 out)
  qkv_gemm_kernel<<<dim3(3, 64, 2), 256, 0, stream>>>(xb, wqkv, qkvb);
  // 2) depthwise 3x3 (bf16 in/out)
  dw_conv3_kernel<<<dim3(1152), 256, 0, stream>>>(qkvb, dw_w, dwb);
  // 3) l2norm + temp*log2e + pack
  norm_pack3_kernel<<<dim3(16, 12, 2), 256, 0, stream>>>(dwb, temp, Qr, Kr, Vs);
  // 4) flash attention v9 (3 waves/SIMD, KVSPLIT=8)
  flash9_kernel<<<dim3(8, 16, KVSPLIT), 256, 0, stream>>>(Qr, Kr, Vs, temp, Opart, Lpart);
  // 5) proj GEMM with fused combine -> d_out (fp32)
  proj_gemm_kernel<<<dim3(1, 256, 2), 256, 0, stream>>>(Opart, Lpart, wproj, (float*)d_out);
}

// Round 11
// 79.531 us; speedup vs baseline: 1.1433x; 1.1433x over previous
//
#include <hip/hip_runtime.h>
#include <cstdint>
#include <cstddef>

#define HW    4096
#define IMG   64
#define DIMC  192
#define NH    4
#define CH    48
#define CPAD  64
#define KVSPLIT 4
#define NTILE (HW / 64 / KVSPLIT)
#define LOG2E 1.4426950408889634f

typedef __bf16 bf16x8 __attribute__((ext_vector_type(8)));
typedef float  f32x4  __attribute__((ext_vector_type(4)));
typedef float  f32x16 __attribute__((ext_vector_type(16)));
typedef unsigned short u16x8 __attribute__((ext_vector_type(8)));
typedef unsigned int   u32x4 __attribute__((ext_vector_type(4)));

#if __has_builtin(__builtin_amdgcn_exp2f)
#define EXP2(x) __builtin_amdgcn_exp2f(x)
#else
#define EXP2(x) exp2f(x)
#endif

__device__ __forceinline__ unsigned short f2bf(float f) {
  unsigned int u = __builtin_bit_cast(unsigned int, f);
  u = (u + 0x7FFFu + ((u >> 16) & 1u)) >> 16;   // RNE
  return (unsigned short)u;
}
__device__ __forceinline__ float bf2f(unsigned short u) {
  return __builtin_bit_cast(float, (unsigned int)u << 16);
}
__device__ __forceinline__ f32x4 mfma16(bf16x8 a, bf16x8 b, f32x4 c) {
  return __builtin_amdgcn_mfma_f32_16x16x32_bf16(a, b, c, 0, 0, 0);
}
__device__ __forceinline__ f32x16 mfma32(bf16x8 a, bf16x8 b, f32x16 c) {
  return __builtin_amdgcn_mfma_f32_32x32x16_bf16(a, b, c, 0, 0, 0);
}
__device__ __forceinline__ void gl16(const void* g, void* l) {
  __builtin_amdgcn_global_load_lds(
      (const __attribute__((address_space(1))) unsigned int*)g,
      (__attribute__((address_space(3))) unsigned int*)l, 16, 0, 0);
}
__device__ __forceinline__ unsigned int cvtpk(float lo, float hi) {
  unsigned int d;
  asm("v_cvt_pk_bf16_f32 %0, %1, %2" : "=v"(d) : "v"(lo), "v"(hi));
  return d;
}
__device__ __forceinline__ void swap32(unsigned int& a, unsigned int& b) {
  asm("v_permlane32_swap_b32 %0, %1" : "+v"(a), "+v"(b));
}

// ---------------------------------------------------------------------------
// P0: pack to chunk-major bf16 (unchanged from R9/R10).
// ---------------------------------------------------------------------------
__global__ __launch_bounds__(256) void pack3_kernel(
    const float* __restrict__ x, const float* __restrict__ qkv_w,
    const float* __restrict__ proj_w, unsigned short* __restrict__ xb,
    unsigned short* __restrict__ wqkv, unsigned short* __restrict__ wproj) {
  const int bx = blockIdx.x, tid = threadIdx.x;
  if (bx < 128) {
    const int it = bx * 256 + tid;        // 0..32767
    const int b = it >> 14;
    const int q4 = (it >> 12) & 3;
    const int p = it & 4095;
    const int c0 = q4 * 48;
    const float* src = x + ((size_t)b * DIMC + c0) * HW + p;
    float v[48];
    #pragma unroll
    for (int j = 0; j < 48; ++j) v[j] = src[(size_t)j * HW];
    #pragma unroll
    for (int g = 0; g < 6; ++g) {
      const int ch = c0 + g * 8;
      const int kc = ch >> 5, off = ch & 31;
      u16x8 gg;
      #pragma unroll
      for (int j = 0; j < 8; ++j) gg[j] = f2bf(v[g * 8 + j]);
      *(u16x8*)(xb + (((size_t)b * 6 + kc) * HW + p) * 32 + off) = gg;
    }
  } else {
    const int row = (bx - 128) * 256 + tid;     // 0..767
    if (row < 576) {
      const float* src = qkv_w + (size_t)row * DIMC;
      #pragma unroll
      for (int kc = 0; kc < 6; ++kc) {
        u16x8 g0, g1, g2, g3;
        #pragma unroll
        for (int j = 0; j < 8; ++j) {
          g0[j] = f2bf(src[kc * 32 + j]);      g1[j] = f2bf(src[kc * 32 + 8 + j]);
          g2[j] = f2bf(src[kc * 32 + 16 + j]); g3[j] = f2bf(src[kc * 32 + 24 + j]);
        }
        unsigned short* dst = wqkv + ((size_t)kc * 576 + row) * 32;
        *(u16x8*)dst = g0; *(u16x8*)(dst + 8) = g1;
        *(u16x8*)(dst + 16) = g2; *(u16x8*)(dst + 24) = g3;
      }
    } else {
      const int oc = row - 576;                // 0..191
      const float* src = proj_w + (size_t)oc * DIMC;
      #pragma unroll
      for (int kc = 0; kc < 6; ++kc) {
        u16x8 g0, g1, g2, g3;
        #pragma unroll
        for (int j = 0; j < 8; ++j) {
          g0[j] = f2bf(src[kc * 32 + j]);      g1[j] = f2bf(src[kc * 32 + 8 + j]);
          g2[j] = f2bf(src[kc * 32 + 16 + j]); g3[j] = f2bf(src[kc * 32 + 24 + j]);
        }
        unsigned short* dst = wproj + ((size_t)kc * DIMC + oc) * 32;
        *(u16x8*)dst = g0; *(u16x8*)(dst + 8) = g1;
        *(u16x8*)(dst + 16) = g2; *(u16x8*)(dst + 24) = g3;
      }
    }
  }
}

// ---------------------------------------------------------------------------
// G1: qkv GEMM, 192-oc blocks (3 sequential subtiles/wave). Grid (3, 64, 2).
// ---------------------------------------------------------------------------
__global__ __launch_bounds__(256) void qkv_gemm_kernel(
    const unsigned short* __restrict__ xb, const unsigned short* __restrict__ wb,
    unsigned short* __restrict__ Cout) {
  const int tid = threadIdx.x;
  const int lane = tid & 63, wv = tid >> 6;
  const int l15 = lane & 15, l4 = lane >> 4;
  const int ocbase = blockIdx.x * 192;
  const int px0 = blockIdx.y * 64;
  const int b   = blockIdx.z;

  f32x4 acc[3][4];
  #pragma unroll
  for (int s = 0; s < 3; ++s)
    #pragma unroll
    for (int p = 0; p < 4; ++p) acc[s][p] = f32x4{0.f, 0.f, 0.f, 0.f};

  #pragma unroll
  for (int kc = 0; kc < 6; ++kc) {
    const unsigned short* xrow = xb + (((size_t)b * 6 + kc) * HW + px0 + l15) * 32 + l4 * 8;
    bf16x8 Bf[4];
    #pragma unroll
    for (int p = 0; p < 4; ++p) Bf[p] = *(const bf16x8*)(xrow + p * 512);
    #pragma unroll
    for (int s = 0; s < 3; ++s) {
      const int oc = ocbase + s * 64 + wv * 16 + l15;
      const bf16x8 af = *(const bf16x8*)(wb + ((size_t)kc * 576 + oc) * 32 + l4 * 8);
      #pragma unroll
      for (int p = 0; p < 4; ++p) acc[s][p] = mfma16(af, Bf[p], acc[s][p]);
    }
  }
  #pragma unroll
  for (int s = 0; s < 3; ++s) {
    unsigned short* Cb = Cout + ((size_t)b * 576 + ocbase + s * 64 + wv * 16) * HW + px0;
    #pragma unroll
    for (int p = 0; p < 4; ++p)
      #pragma unroll
      for (int r = 0; r < 4; ++r)
        Cb[(size_t)(l4 * 4 + r) * HW + p * 16 + l15] = f2bf(acc[s][p][r]);
  }
}

// ---------------------------------------------------------------------------
// K2: depthwise 3x3, 2 x-outputs/thread, ushort2 stores (doubled width).
// Thread = (x-pair 0..31, 8-row group 0..7). Arithmetic per element identical.
// ---------------------------------------------------------------------------
__global__ __launch_bounds__(256) void dw_conv4_kernel(
    const unsigned short* __restrict__ X, const float* __restrict__ W,
    unsigned short* __restrict__ Y) {
  __shared__ float T[66][72];
  const int bc = blockIdx.x;            // b*576 + ch
  const int ch = bc % 576;
  const int tid = threadIdx.x;
  const unsigned short* Xb = X + (size_t)bc * HW;
  #pragma unroll
  for (int i = 0; i < 4; ++i) {
    const int idx = i * 256 + tid;      // quads
    const int row = idx >> 4, c4 = (idx & 15) << 2;
    const ushort4 u = *(const ushort4*)(Xb + row * 64 + c4);
    float4 f; f.x = bf2f(u.x); f.y = bf2f(u.y); f.z = bf2f(u.z); f.w = bf2f(u.w);
    *(float4*)&T[row + 1][c4 + 4] = f;
  }
  if (tid < 72) { T[0][tid] = 0.f; T[65][tid] = 0.f; }
  if (tid >= 128 && tid < 194) { const int r = tid - 128; T[r][3] = 0.f; T[r][68] = 0.f; }
  float w[9];
  #pragma unroll
  for (int i = 0; i < 9; ++i) w[i] = W[ch * 9 + i];
  __syncthreads();

  const int x2 = tid & 31, yg = tid >> 5;
  const int c = x2 * 2 + 4;             // LDS col of left output's center
  const int ys = yg * 8;
  float a0 = T[ys][c - 1],     a1 = T[ys][c],     a2 = T[ys][c + 1],     a3 = T[ys][c + 2];
  float b0 = T[ys + 1][c - 1], b1 = T[ys + 1][c], b2 = T[ys + 1][c + 1], b3 = T[ys + 1][c + 2];
  unsigned short* Yb = Y + (size_t)bc * HW;
  #pragma unroll
  for (int k = 0; k < 8; ++k) {
    const float c0 = T[ys + k + 2][c - 1], c1 = T[ys + k + 2][c];
    const float c2 = T[ys + k + 2][c + 1], c3 = T[ys + k + 2][c + 2];
    const float s0 = w[0] * a0 + w[1] * a1 + w[2] * a2
                   + w[3] * b0 + w[4] * b1 + w[5] * b2
                   + w[6] * c0 + w[7] * c1 + w[8] * c2;
    const float s1 = w[0] * a1 + w[1] * a2 + w[2] * a3
                   + w[3] * b1 + w[4] * b2 + w[5] * b3
                   + w[6] * c1 + w[7] * c2 + w[8] * c3;
    ushort2 st; st.x = f2bf(s0); st.y = f2bf(s1);
    *(ushort2*)(Yb + (ys + k) * 64 + x2 * 2) = st;
    a0 = b0; a1 = b1; a2 = b2; a3 = b3;
    b0 = c0; b1 = c1; b2 = c2; b3 = c3;
  }
}

// ---------------------------------------------------------------------------
// K3: l2norm + temp*log2e + pack, 2 px/thread with ushort2 loads.
// Grid (16, 12 = sel*4+h, 2), block 128. Layouts unchanged.
// ---------------------------------------------------------------------------
__global__ __launch_bounds__(128) void norm_pack4_kernel(
    const unsigned short* __restrict__ Dw, const float* __restrict__ temp,
    unsigned short* __restrict__ Qr, unsigned short* __restrict__ Kr,
    unsigned short* __restrict__ Vs) {
  const int px = blockIdx.x * 256 + threadIdx.x * 2;
  const int sel = blockIdx.y >> 2, h = blockIdx.y & 3;
  const int b = blockIdx.z;
  const int bh = b * NH + h;
  const unsigned short* base = Dw + ((size_t)b * 576 + sel * DIMC + h * CH) * HW + px;

  if (sel == 2) {  // V: no norm; swizzle keeps even/odd adjacent -> ushort2
    const int kt = px & ~63, kl = px & 63;
    #pragma unroll
    for (int c = 0; c < CH; ++c) {
      const ushort2 u = *(const ushort2*)(base + (size_t)c * HW);
      *(ushort2*)(Vs + ((size_t)bh * CH + c) * HW + kt + (kl ^ ((c & 7) << 3))) = u;
    }
    return;
  }
  float v0[CH], v1[CH];
  float ss0 = 0.f, ss1 = 0.f;
  #pragma unroll
  for (int j = 0; j < CH; ++j) {
    const ushort2 u = *(const ushort2*)(base + (size_t)j * HW);
    v0[j] = bf2f(u.x); v1[j] = bf2f(u.y);
    ss0 += v0[j] * v0[j]; ss1 += v1[j] * v1[j];
  }
  float sc0, sc1;
  if (sel == 0) {
    const float tl = temp[h] * LOG2E;
    sc0 = tl / fmaxf(sqrtf(ss0), 1e-12f);
    sc1 = tl / fmaxf(sqrtf(ss1), 1e-12f);
  } else {
    sc0 = 1.0f / fmaxf(sqrtf(ss0), 1e-12f);
    sc1 = 1.0f / fmaxf(sqrtf(ss1), 1e-12f);
  }
  const u16x8 zz = {0, 0, 0, 0, 0, 0, 0, 0};
  #pragma unroll
  for (int e = 0; e < 2; ++e) {
    const float* vv = e ? v1 : v0;
    const float sc = e ? sc1 : sc0;
    u16x8 gr[8];
    #pragma unroll
    for (int g = 0; g < 6; ++g)
      #pragma unroll
      for (int j = 0; j < 8; ++j) gr[g][j] = f2bf(vv[g * 8 + j] * sc);
    gr[6] = zz; gr[7] = zz;
    if (sel == 0) {
      unsigned short* qrow = Qr + ((size_t)bh * HW + px + e) * CPAD;
      #pragma unroll
      for (int g = 0; g < 8; ++g) *(u16x8*)(qrow + g * 8) = gr[g];
    } else {
      const int pe = px + e;
      const int ksw = (pe & 3) | (((pe >> 3) & 1) << 2);
      unsigned short* krow = Kr + ((size_t)bh * HW + pe) * CPAD;
      #pragma unroll
      for (int g = 0; g < 8; ++g) *(u16x8*)(krow + (g ^ ksw) * 8) = gr[g];
    }
  }
}

// ---------------------------------------------------------------------------
// K4: flash attention v8 (R9 verbatim) — 32x32x16 MFMA, exp2/PV interleaved,
// KVSPLIT=4, launch_bounds(256,2).
// ---------------------------------------------------------------------------
__global__ __launch_bounds__(256, 2) void flash8_kernel(
    const unsigned short* __restrict__ Qr,
    const unsigned short* __restrict__ Kr,
    const unsigned short* __restrict__ Vs,
    const float* __restrict__ temp,
    unsigned short* __restrict__ Opart, float* __restrict__ Lpart) {
  __shared__ __align__(16) union {
    struct { unsigned short Kl[2][4096]; unsigned short Vl[2][4096]; } s;
    float T[256][53];
  } lds;
  const int tid = threadIdx.x;
  const int lane = tid & 63, wv = tid >> 6;
  const int l31 = lane & 31, lhi = lane >> 5;
  const int bh = blockIdx.x, qt = blockIdx.y, sp = blockIdx.z;
  const int qb = qt * 256 + wv * 64;
  const float m = fabsf(temp[bh & 3]) * LOG2E * 1.05f + 0.1f;

  for (int i = tid; i < 1024; i += 256) {
    const unsigned short vv = (i < 64) ? (unsigned short)0x3F80 : (unsigned short)0;
    lds.s.Vl[0][3072 + i] = vv;
    lds.s.Vl[1][3072 + i] = vv;
  }

  const unsigned short* Qb = Qr + ((size_t)bh * HW + qb) * CPAD;
  bf16x8 qf[2][3];
  #pragma unroll
  for (int qb2 = 0; qb2 < 2; ++qb2)
    #pragma unroll
    for (int ci = 0; ci < 3; ++ci)
      qf[qb2][ci] = *(const bf16x8*)(Qb + (size_t)(qb2 * 32 + l31) * CPAD + ci * 16 + lhi * 8);

  const char* kg = (const char*)Kr + ((size_t)bh * HW + (size_t)sp * (HW / KVSPLIT)) * 128;
  const char* vg = (const char*)Vs + (size_t)bh * CH * HW * 2 + (size_t)sp * (HW / KVSPLIT) * 2;
  const int koA = tid * 16;
  const int vgA = (tid >> 3) * 8192 + (tid & 7) * 16;
  const int vgB = (32 + (tid >> 3)) * 8192 + (tid & 7) * 16;

  auto stage = [&](int buf, const char* kp, const char* vp) {
    char* kl = (char*)&lds.s.Kl[buf][0];
    gl16(kp + koA,        kl + koA);
    gl16(kp + 4096 + koA, kl + 4096 + koA);
    char* vl = (char*)&lds.s.Vl[buf][0];
    gl16(vp + vgA, vl + tid * 16);
    if (tid < 128) gl16(vp + vgB, vl + 4096 + tid * 16);
  };

  f32x16 o[2][2];
  #pragma unroll
  for (int cb = 0; cb < 2; ++cb)
    #pragma unroll
    for (int qb2 = 0; qb2 < 2; ++qb2)
      #pragma unroll
      for (int i = 0; i < 16; ++i) o[cb][qb2][i] = 0.f;
  f32x16 zin;
  #pragma unroll
  for (int i = 0; i < 16; ++i) zin[i] = -m;

  stage(0, kg, vg);
  kg += 8192; vg += 128;
  __syncthreads();
  int cur = 0;
  for (int t = 0; t < NTILE; ++t) {
    if (t + 1 < NTILE) { stage(cur ^ 1, kg, vg); kg += 8192; vg += 128; }
    const unsigned short* KL = &lds.s.Kl[cur][0];
    const unsigned short* VL = &lds.s.Vl[cur][0];

    f32x16 S[2][2];
    __builtin_amdgcn_s_setprio(1);
    #pragma unroll
    for (int kb = 0; kb < 2; ++kb) {
      const int krow = kb * 32 + l31;
      const int ksw = (krow & 3) | (((krow >> 3) & 1) << 2);
      bf16x8 kf[3];
      #pragma unroll
      for (int ci = 0; ci < 3; ++ci)
        kf[ci] = *(const bf16x8*)(KL + krow * 64 + (((ci * 2 + lhi) ^ ksw) * 8));
      #pragma unroll
      for (int qb2 = 0; qb2 < 2; ++qb2) {
        f32x16 acc = zin;
        #pragma unroll
        for (int ci = 0; ci < 3; ++ci) acc = mfma32(kf[ci], qf[qb2][ci], acc);
        S[kb][qb2] = acc;
      }
    }
    __builtin_amdgcn_s_setprio(0);

    #pragma unroll
    for (int kb = 0; kb < 2; ++kb) {
      #pragma unroll
      for (int qb2 = 0; qb2 < 2; ++qb2)
        #pragma unroll
        for (int i = 0; i < 16; ++i) S[kb][qb2][i] = EXP2(S[kb][qb2][i]);

      #pragma unroll
      for (int kh = 0; kh < 2; ++kh) {            // kc = kb*2 + kh
        const int kc = kb * 2 + kh, rb = kh * 8;
        bf16x8 pb[2];
        #pragma unroll
        for (int qb2 = 0; qb2 < 2; ++qb2) {
          unsigned int w0 = cvtpk(S[kb][qb2][rb + 0], S[kb][qb2][rb + 1]);
          unsigned int w1 = cvtpk(S[kb][qb2][rb + 2], S[kb][qb2][rb + 3]);
          unsigned int w2 = cvtpk(S[kb][qb2][rb + 4], S[kb][qb2][rb + 5]);
          unsigned int w3 = cvtpk(S[kb][qb2][rb + 6], S[kb][qb2][rb + 7]);
          swap32(w0, w2);
          swap32(w1, w3);
          u32x4 ww = {w0, w1, w2, w3};
          pb[qb2] = __builtin_bit_cast(bf16x8, ww);
        }
        __builtin_amdgcn_s_setprio(1);
        #pragma unroll
        for (int cb = 0; cb < 2; ++cb) {
          const int crow = cb * 32 + l31;
          const bf16x8 vf = *(const bf16x8*)(VL + crow * 64 + (((kc * 2 + lhi) ^ (crow & 7)) * 8));
          #pragma unroll
          for (int qb2 = 0; qb2 < 2; ++qb2) o[cb][qb2] = mfma32(vf, pb[qb2], o[cb][qb2]);
        }
        __builtin_amdgcn_s_setprio(0);
      }
    }
    __syncthreads();
    cur ^= 1;
  }

  #pragma unroll
  for (int cb = 0; cb < 2; ++cb)
    #pragma unroll
    for (int qb2 = 0; qb2 < 2; ++qb2) {
      const int ql = wv * 64 + qb2 * 32 + l31;
      #pragma unroll
      for (int r = 0; r < 16; ++r) {
        const int c = cb * 32 + (r & 3) + 8 * (r >> 2) + 4 * lhi;
        if (c < 48) lds.T[ql][c] = o[cb][qb2][r];
      }
      if (lhi == 0) lds.T[ql][48] = o[1][qb2][8];
    }
  __syncthreads();
  {
    const int ql = tid;
    const int qg = qt * 256 + ql;
    float vv[48];
    #pragma unroll
    for (int c = 0; c < 48; ++c) vv[c] = lds.T[ql][c];
    const float Lv = lds.T[ql][48];
    unsigned short* Ob = Opart + ((size_t)(sp * 8 + bh) * HW + qg) * 48;
    #pragma unroll
    for (int g = 0; g < 6; ++g) {
      u16x8 gg;
      #pragma unroll
      for (int j = 0; j < 8; ++j) gg[j] = f2bf(vv[g * 8 + j]);
      *(u16x8*)(Ob + g * 8) = gg;
    }
    Lpart[(size_t)(sp * 8 + bh) * HW + qg] = Lv;
  }
}

// ---------------------------------------------------------------------------
// G2: proj GEMM with fused split-combine (4 splits), px-tile 16,
// grid (1,256,2) = 512 blocks.
// ---------------------------------------------------------------------------
__global__ __launch_bounds__(256) void proj_gemm_kernel(
    const unsigned short* __restrict__ Opart, const float* __restrict__ Lpart,
    const unsigned short* __restrict__ wb, float* __restrict__ Cout) {
  const int tid = threadIdx.x;
  const int lane = tid & 63, wv = tid >> 6;
  const int l15 = lane & 15, l4 = lane >> 4;
  const int px0 = blockIdx.y * 16;
  const int b   = blockIdx.z;

  bf16x8 Bf[6];
  #pragma unroll
  for (int kc = 0; kc < 6; ++kc) {
    const int ch0 = kc * 32 + l4 * 8;
    const int head = ch0 / 48, off = ch0 % 48;
    const int px = px0 + l15;
    float ls = 0.f;
    #pragma unroll
    for (int sp = 0; sp < KVSPLIT; ++sp)
      ls += Lpart[(size_t)(sp * 8 + b * 4 + head) * HW + px];
    const float inv = 1.f / ls;
    float a8[8] = {};
    #pragma unroll
    for (int sp = 0; sp < KVSPLIT; ++sp) {
      const u16x8 u = *(const u16x8*)(Opart +
          ((size_t)(sp * 8 + b * 4 + head) * HW + px) * 48 + off);
      #pragma unroll
      for (int j = 0; j < 8; ++j) a8[j] += bf2f(u[j]);
    }
    u16x8 g;
    #pragma unroll
    for (int j = 0; j < 8; ++j) g[j] = f2bf(a8[j] * inv);
    Bf[kc] = __builtin_bit_cast(bf16x8, g);
  }
  #pragma unroll
  for (int s = 0; s < 3; ++s) {
    const int oc = s * 64 + wv * 16 + l15;
    f32x4 acc = {0.f, 0.f, 0.f, 0.f};
    #pragma unroll
    for (int kc = 0; kc < 6; ++kc) {
      const bf16x8 af = *(const bf16x8*)(wb + ((size_t)kc * DIMC + oc) * 32 + l4 * 8);
      acc = mfma16(af, Bf[kc], acc);
    }
    float* Cb = Cout + ((size_t)b * DIMC + s * 64 + wv * 16) * HW + px0;
    #pragma unroll
    for (int r = 0; r < 4; ++r)
      Cb[(size_t)(l4 * 4 + r) * HW + l15] = acc[r];
  }
}

// ---------------------------------------------------------------------------
extern "C" void kernel_launch(void* const* d_in, const int* in_sizes, int n_in,
                              void* d_out, int out_size, void* d_ws, size_t ws_size,
                              hipStream_t stream) {
  const float* x      = (const float*)d_in[0];
  const float* qkv_w  = (const float*)d_in[1];
  const float* dw_w   = (const float*)d_in[2];
  const float* proj_w = (const float*)d_in[3];
  const float* temp   = (const float*)d_in[4];

  char* ws = (char*)d_ws;
  unsigned short* xb    = (unsigned short*)(ws);              //  3,145,728
  unsigned short* wqkv  = (unsigned short*)(ws + 3145728);    //    221,184
  unsigned short* wproj = (unsigned short*)(ws + 3366912);    //     73,728
  unsigned short* qkvb  = (unsigned short*)(ws + 3440640);    //  9,437,184
  unsigned short* dwb   = (unsigned short*)(ws + 12877824);   //  9,437,184
  unsigned short* Qr    = (unsigned short*)(ws + 22315008);   //  4,194,304
  unsigned short* Kr    = (unsigned short*)(ws + 26509312);   //  4,194,304
  unsigned short* Vs    = (unsigned short*)(ws + 30703616);   //  3,145,728
  unsigned short* Opart = (unsigned short*)(ws + 33849344);   // 12,582,912  [sp=4][bh][q][48]
  float*          Lpart = (float*)(ws + 46432256);            //    524,288

  // 0) pack x + weights to chunk-major bf16
  pack3_kernel<<<dim3(131), 256, 0, stream>>>(x, qkv_w, proj_w, xb, wqkv, wproj);
  // 1) qkv 1x1 conv (bf16 MFMA GEMM, bf16 out)
  qkv_gemm_kernel<<<dim3(3, 64, 2), 256, 0, stream>>>(xb, wqkv, qkvb);
  // 2) depthwise 3x3 (2 px/thread, ushort2 stores)
  dw_conv4_kernel<<<dim3(1152), 256, 0, stream>>>(qkvb, dw_w, dwb);
  // 3) l2norm + temp*log2e + pack (2 px/thread, ushort2 loads)
  norm_pack4_kernel<<<dim3(16, 12, 2), 128, 0, stream>>>(dwb, temp, Qr, Kr, Vs);
  // 4) flash attention v8 (KVSPLIT=4, 2 blocks/CU)
  flash8_kernel<<<dim3(8, 16, KVSPLIT), 256, 0, stream>>>(Qr, Kr, Vs, temp, Opart, Lpart);
  // 5) proj GEMM with fused combine -> d_out (fp32)
  proj_gemm_kernel<<<dim3(1, 256, 2), 256, 0, stream>>>(Opart, Lpart, wproj, (float*)d_out);
}

// Round 12
// 78.546 us; speedup vs baseline: 1.1577x; 1.0125x over previous
//
#include <hip/hip_runtime.h>
#include <cstdint>
#include <cstddef>

#define HW    4096
#define IMG   64
#define DIMC  192
#define NH    4
#define CH    48
#define CPAD  64
#define KVSPLIT 4
#define NTILE (HW / 64 / KVSPLIT)
#define LOG2E 1.4426950408889634f

typedef __bf16 bf16x8 __attribute__((ext_vector_type(8)));
typedef float  f32x4  __attribute__((ext_vector_type(4)));
typedef float  f32x16 __attribute__((ext_vector_type(16)));
typedef unsigned short u16x8 __attribute__((ext_vector_type(8)));
typedef unsigned int   u32x4 __attribute__((ext_vector_type(4)));

#if __has_builtin(__builtin_amdgcn_exp2f)
#define EXP2(x) __builtin_amdgcn_exp2f(x)
#else
#define EXP2(x) exp2f(x)
#endif

__device__ __forceinline__ unsigned short f2bf(float f) {
  unsigned int u = __builtin_bit_cast(unsigned int, f);
  u = (u + 0x7FFFu + ((u >> 16) & 1u)) >> 16;   // RNE
  return (unsigned short)u;
}
__device__ __forceinline__ float bf2f(unsigned short u) {
  return __builtin_bit_cast(float, (unsigned int)u << 16);
}
__device__ __forceinline__ f32x4 mfma16(bf16x8 a, bf16x8 b, f32x4 c) {
  return __builtin_amdgcn_mfma_f32_16x16x32_bf16(a, b, c, 0, 0, 0);
}
__device__ __forceinline__ f32x16 mfma32(bf16x8 a, bf16x8 b, f32x16 c) {
  return __builtin_amdgcn_mfma_f32_32x32x16_bf16(a, b, c, 0, 0, 0);
}
__device__ __forceinline__ void gl16(const void* g, void* l) {
  __builtin_amdgcn_global_load_lds(
      (const __attribute__((address_space(1))) unsigned int*)g,
      (__attribute__((address_space(3))) unsigned int*)l, 16, 0, 0);
}
__device__ __forceinline__ unsigned int cvtpk(float lo, float hi) {
  unsigned int d;
  asm("v_cvt_pk_bf16_f32 %0, %1, %2" : "=v"(d) : "v"(lo), "v"(hi));
  return d;
}
__device__ __forceinline__ void swap32(unsigned int& a, unsigned int& b) {
  asm("v_permlane32_swap_b32 %0, %1" : "+v"(a), "+v"(b));
}

// ---------------------------------------------------------------------------
// P0: pack to chunk-major bf16 (R9 verbatim).
// ---------------------------------------------------------------------------
__global__ __launch_bounds__(256) void pack3_kernel(
    const float* __restrict__ x, const float* __restrict__ qkv_w,
    const float* __restrict__ proj_w, unsigned short* __restrict__ xb,
    unsigned short* __restrict__ wqkv, unsigned short* __restrict__ wproj) {
  const int bx = blockIdx.x, tid = threadIdx.x;
  if (bx < 128) {
    const int it = bx * 256 + tid;        // 0..32767
    const int b = it >> 14;
    const int q4 = (it >> 12) & 3;
    const int p = it & 4095;
    const int c0 = q4 * 48;
    const float* src = x + ((size_t)b * DIMC + c0) * HW + p;
    float v[48];
    #pragma unroll
    for (int j = 0; j < 48; ++j) v[j] = src[(size_t)j * HW];
    #pragma unroll
    for (int g = 0; g < 6; ++g) {
      const int ch = c0 + g * 8;
      const int kc = ch >> 5, off = ch & 31;
      u16x8 gg;
      #pragma unroll
      for (int j = 0; j < 8; ++j) gg[j] = f2bf(v[g * 8 + j]);
      *(u16x8*)(xb + (((size_t)b * 6 + kc) * HW + p) * 32 + off) = gg;
    }
  } else {
    const int row = (bx - 128) * 256 + tid;     // 0..767
    if (row < 576) {
      const float* src = qkv_w + (size_t)row * DIMC;
      #pragma unroll
      for (int kc = 0; kc < 6; ++kc) {
        u16x8 g0, g1, g2, g3;
        #pragma unroll
        for (int j = 0; j < 8; ++j) {
          g0[j] = f2bf(src[kc * 32 + j]);      g1[j] = f2bf(src[kc * 32 + 8 + j]);
          g2[j] = f2bf(src[kc * 32 + 16 + j]); g3[j] = f2bf(src[kc * 32 + 24 + j]);
        }
        unsigned short* dst = wqkv + ((size_t)kc * 576 + row) * 32;
        *(u16x8*)dst = g0; *(u16x8*)(dst + 8) = g1;
        *(u16x8*)(dst + 16) = g2; *(u16x8*)(dst + 24) = g3;
      }
    } else {
      const int oc = row - 576;                // 0..191
      const float* src = proj_w + (size_t)oc * DIMC;
      #pragma unroll
      for (int kc = 0; kc < 6; ++kc) {
        u16x8 g0, g1, g2, g3;
        #pragma unroll
        for (int j = 0; j < 8; ++j) {
          g0[j] = f2bf(src[kc * 32 + j]);      g1[j] = f2bf(src[kc * 32 + 8 + j]);
          g2[j] = f2bf(src[kc * 32 + 16 + j]); g3[j] = f2bf(src[kc * 32 + 24 + j]);
        }
        unsigned short* dst = wproj + ((size_t)kc * DIMC + oc) * 32;
        *(u16x8*)dst = g0; *(u16x8*)(dst + 8) = g1;
        *(u16x8*)(dst + 16) = g2; *(u16x8*)(dst + 24) = g3;
      }
    }
  }
}

// ---------------------------------------------------------------------------
// G1: qkv GEMM, 192-oc blocks (3 sequential subtiles/wave). Grid (3, 64, 2).
// ---------------------------------------------------------------------------
__global__ __launch_bounds__(256) void qkv_gemm_kernel(
    const unsigned short* __restrict__ xb, const unsigned short* __restrict__ wb,
    unsigned short* __restrict__ Cout) {
  const int tid = threadIdx.x;
  const int lane = tid & 63, wv = tid >> 6;
  const int l15 = lane & 15, l4 = lane >> 4;
  const int ocbase = blockIdx.x * 192;
  const int px0 = blockIdx.y * 64;
  const int b   = blockIdx.z;

  f32x4 acc[3][4];
  #pragma unroll
  for (int s = 0; s < 3; ++s)
    #pragma unroll
    for (int p = 0; p < 4; ++p) acc[s][p] = f32x4{0.f, 0.f, 0.f, 0.f};

  #pragma unroll
  for (int kc = 0; kc < 6; ++kc) {
    const unsigned short* xrow = xb + (((size_t)b * 6 + kc) * HW + px0 + l15) * 32 + l4 * 8;
    bf16x8 Bf[4];
    #pragma unroll
    for (int p = 0; p < 4; ++p) Bf[p] = *(const bf16x8*)(xrow + p * 512);
    #pragma unroll
    for (int s = 0; s < 3; ++s) {
      const int oc = ocbase + s * 64 + wv * 16 + l15;
      const bf16x8 af = *(const bf16x8*)(wb + ((size_t)kc * 576 + oc) * 32 + l4 * 8);
      #pragma unroll
      for (int p = 0; p < 4; ++p) acc[s][p] = mfma16(af, Bf[p], acc[s][p]);
    }
  }
  #pragma unroll
  for (int s = 0; s < 3; ++s) {
    unsigned short* Cb = Cout + ((size_t)b * 576 + ocbase + s * 64 + wv * 16) * HW + px0;
    #pragma unroll
    for (int p = 0; p < 4; ++p)
      #pragma unroll
      for (int r = 0; r < 4; ++r)
        Cb[(size_t)(l4 * 4 + r) * HW + p * 16 + l15] = f2bf(acc[s][p][r]);
  }
}

// ---------------------------------------------------------------------------
// K2: depthwise 3x3 (R9 verbatim).
// ---------------------------------------------------------------------------
__global__ __launch_bounds__(256) void dw_conv3_kernel(
    const unsigned short* __restrict__ X, const float* __restrict__ W,
    unsigned short* __restrict__ Y) {
  __shared__ float T[66][72];
  const int bc = blockIdx.x;            // b*576 + ch
  const int ch = bc % 576;
  const int tid = threadIdx.x;
  const unsigned short* Xb = X + (size_t)bc * HW;
  #pragma unroll
  for (int i = 0; i < 4; ++i) {
    const int idx = i * 256 + tid;      // quads
    const int row = idx >> 4, c4 = (idx & 15) << 2;
    const ushort4 u = *(const ushort4*)(Xb + row * 64 + c4);
    float4 f; f.x = bf2f(u.x); f.y = bf2f(u.y); f.z = bf2f(u.z); f.w = bf2f(u.w);
    *(float4*)&T[row + 1][c4 + 4] = f;
  }
  if (tid < 72) { T[0][tid] = 0.f; T[65][tid] = 0.f; }
  if (tid >= 128 && tid < 194) { const int r = tid - 128; T[r][3] = 0.f; T[r][68] = 0.f; }
  float w[9];
  #pragma unroll
  for (int i = 0; i < 9; ++i) w[i] = W[ch * 9 + i];
  __syncthreads();

  const int xx = tid & 63, ys = (tid >> 6) << 4;
  const int c = xx + 4;
  float a0 = T[ys][c - 1],     a1 = T[ys][c],     a2 = T[ys][c + 1];
  float b0 = T[ys + 1][c - 1], b1 = T[ys + 1][c], b2 = T[ys + 1][c + 1];
  unsigned short* Yb = Y + (size_t)bc * HW;
  #pragma unroll
  for (int k = 0; k < 16; ++k) {
    const float c0 = T[ys + k + 2][c - 1], c1 = T[ys + k + 2][c], c2 = T[ys + k + 2][c + 1];
    const float s = w[0] * a0 + w[1] * a1 + w[2] * a2
                  + w[3] * b0 + w[4] * b1 + w[5] * b2
                  + w[6] * c0 + w[7] * c1 + w[8] * c2;
    Yb[(ys + k) * 64 + xx] = f2bf(s);
    a0 = b0; a1 = b1; a2 = b2; b0 = c0; b1 = c1; b2 = c2;
  }
}

// ---------------------------------------------------------------------------
// K3: l2norm + temp*log2e + pack (R9 verbatim).
// ---------------------------------------------------------------------------
__global__ __launch_bounds__(256) void norm_pack3_kernel(
    const unsigned short* __restrict__ Dw, const float* __restrict__ temp,
    unsigned short* __restrict__ Qr, unsigned short* __restrict__ Kr,
    unsigned short* __restrict__ Vs) {
  const int px = blockIdx.x * 256 + threadIdx.x;
  const int sel = blockIdx.y >> 2, h = blockIdx.y & 3;
  const int b = blockIdx.z;
  const int bh = b * NH + h;
  const unsigned short* base = Dw + ((size_t)b * 576 + sel * DIMC + h * CH) * HW + px;

  float v[CH];
  if (sel == 2) {  // V: no norm
    const int kt = px & ~63, kl = px & 63;
    #pragma unroll
    for (int c = 0; c < CH; ++c)
      Vs[((size_t)bh * CH + c) * HW + kt + (kl ^ ((c & 7) << 3))] = base[(size_t)c * HW];
    return;
  }
  float ss = 0.f;
  #pragma unroll
  for (int j = 0; j < CH; ++j) { v[j] = bf2f(base[(size_t)j * HW]); ss += v[j] * v[j]; }
  const u16x8 zz = {0, 0, 0, 0, 0, 0, 0, 0};
  if (sel == 0) {  // Q: fold temperature*log2e
    const float sc = temp[h] * LOG2E / fmaxf(sqrtf(ss), 1e-12f);
    u16x8 gr[8];
    #pragma unroll
    for (int g = 0; g < 6; ++g)
      #pragma unroll
      for (int j = 0; j < 8; ++j) gr[g][j] = f2bf(v[g * 8 + j] * sc);
    gr[6] = zz; gr[7] = zz;
    unsigned short* qrow = Qr + ((size_t)bh * HW + px) * CPAD;
    #pragma unroll
    for (int g = 0; g < 8; ++g) *(u16x8*)(qrow + g * 8) = gr[g];
  } else {         // K: swizzled granules
    const int ksw = (px & 3) | (((px >> 3) & 1) << 2);
    const float sc = 1.0f / fmaxf(sqrtf(ss), 1e-12f);
    u16x8 gr[8];
    #pragma unroll
    for (int g = 0; g < 6; ++g)
      #pragma unroll
      for (int j = 0; j < 8; ++j) gr[g][j] = f2bf(v[g * 8 + j] * sc);
    gr[6] = zz; gr[7] = zz;
    unsigned short* krow = Kr + ((size_t)bh * HW + px) * CPAD;
    #pragma unroll
    for (int g = 0; g < 8; ++g) *(u16x8*)(krow + (g ^ ksw) * 8) = gr[g];
  }
}

// ---------------------------------------------------------------------------
// K4: flash attention v8 (R9 verbatim) — 32x32x16 MFMA, exp2/PV interleaved,
// KVSPLIT=4, launch_bounds(256,2).
// ---------------------------------------------------------------------------
__global__ __launch_bounds__(256, 2) void flash8_kernel(
    const unsigned short* __restrict__ Qr,
    const unsigned short* __restrict__ Kr,
    const unsigned short* __restrict__ Vs,
    const float* __restrict__ temp,
    unsigned short* __restrict__ Opart, float* __restrict__ Lpart) {
  __shared__ __align__(16) union {
    struct { unsigned short Kl[2][4096]; unsigned short Vl[2][4096]; } s;
    float T[256][53];
  } lds;
  const int tid = threadIdx.x;
  const int lane = tid & 63, wv = tid >> 6;
  const int l31 = lane & 31, lhi = lane >> 5;
  const int bh = blockIdx.x, qt = blockIdx.y, sp = blockIdx.z;
  const int qb = qt * 256 + wv * 64;
  const float m = fabsf(temp[bh & 3]) * LOG2E * 1.05f + 0.1f;

  for (int i = tid; i < 1024; i += 256) {
    const unsigned short vv = (i < 64) ? (unsigned short)0x3F80 : (unsigned short)0;
    lds.s.Vl[0][3072 + i] = vv;
    lds.s.Vl[1][3072 + i] = vv;
  }

  const unsigned short* Qb = Qr + ((size_t)bh * HW + qb) * CPAD;
  bf16x8 qf[2][3];
  #pragma unroll
  for (int qb2 = 0; qb2 < 2; ++qb2)
    #pragma unroll
    for (int ci = 0; ci < 3; ++ci)
      qf[qb2][ci] = *(const bf16x8*)(Qb + (size_t)(qb2 * 32 + l31) * CPAD + ci * 16 + lhi * 8);

  const char* kg = (const char*)Kr + ((size_t)bh * HW + (size_t)sp * (HW / KVSPLIT)) * 128;
  const char* vg = (const char*)Vs + (size_t)bh * CH * HW * 2 + (size_t)sp * (HW / KVSPLIT) * 2;
  const int koA = tid * 16;
  const int vgA = (tid >> 3) * 8192 + (tid & 7) * 16;
  const int vgB = (32 + (tid >> 3)) * 8192 + (tid & 7) * 16;

  auto stage = [&](int buf, const char* kp, const char* vp) {
    char* kl = (char*)&lds.s.Kl[buf][0];
    gl16(kp + koA,        kl + koA);
    gl16(kp + 4096 + koA, kl + 4096 + koA);
    char* vl = (char*)&lds.s.Vl[buf][0];
    gl16(vp + vgA, vl + tid * 16);
    if (tid < 128) gl16(vp + vgB, vl + 4096 + tid * 16);
  };

  f32x16 o[2][2];
  #pragma unroll
  for (int cb = 0; cb < 2; ++cb)
    #pragma unroll
    for (int qb2 = 0; qb2 < 2; ++qb2)
      #pragma unroll
      for (int i = 0; i < 16; ++i) o[cb][qb2][i] = 0.f;
  f32x16 zin;
  #pragma unroll
  for (int i = 0; i < 16; ++i) zin[i] = -m;

  stage(0, kg, vg);
  kg += 8192; vg += 128;
  __syncthreads();
  int cur = 0;
  for (int t = 0; t < NTILE; ++t) {
    if (t + 1 < NTILE) { stage(cur ^ 1, kg, vg); kg += 8192; vg += 128; }
    const unsigned short* KL = &lds.s.Kl[cur][0];
    const unsigned short* VL = &lds.s.Vl[cur][0];

    f32x16 S[2][2];
    __builtin_amdgcn_s_setprio(1);
    #pragma unroll
    for (int kb = 0; kb < 2; ++kb) {
      const int krow = kb * 32 + l31;
      const int ksw = (krow & 3) | (((krow >> 3) & 1) << 2);
      bf16x8 kf[3];
      #pragma unroll
      for (int ci = 0; ci < 3; ++ci)
        kf[ci] = *(const bf16x8*)(KL + krow * 64 + (((ci * 2 + lhi) ^ ksw) * 8));
      #pragma unroll
      for (int qb2 = 0; qb2 < 2; ++qb2) {
        f32x16 acc = zin;
        #pragma unroll
        for (int ci = 0; ci < 3; ++ci) acc = mfma32(kf[ci], qf[qb2][ci], acc);
        S[kb][qb2] = acc;
      }
    }
    __builtin_amdgcn_s_setprio(0);

    #pragma unroll
    for (int kb = 0; kb < 2; ++kb) {
      #pragma unroll
      for (int qb2 = 0; qb2 < 2; ++qb2)
        #pragma unroll
        for (int i = 0; i < 16; ++i) S[kb][qb2][i] = EXP2(S[kb][qb2][i]);

      #pragma unroll
      for (int kh = 0; kh < 2; ++kh) {            // kc = kb*2 + kh
        const int kc = kb * 2 + kh, rb = kh * 8;
        bf16x8 pb[2];
        #pragma unroll
        for (int qb2 = 0; qb2 < 2; ++qb2) {
          unsigned int w0 = cvtpk(S[kb][qb2][rb + 0], S[kb][qb2][rb + 1]);
          unsigned int w1 = cvtpk(S[kb][qb2][rb + 2], S[kb][qb2][rb + 3]);
          unsigned int w2 = cvtpk(S[kb][qb2][rb + 4], S[kb][qb2][rb + 5]);
          unsigned int w3 = cvtpk(S[kb][qb2][rb + 6], S[kb][qb2][rb + 7]);
          swap32(w0, w2);
          swap32(w1, w3);
          u32x4 ww = {w0, w1, w2, w3};
          pb[qb2] = __builtin_bit_cast(bf16x8, ww);
        }
        __builtin_amdgcn_s_setprio(1);
        #pragma unroll
        for (int cb = 0; cb < 2; ++cb) {
          const int crow = cb * 32 + l31;
          const bf16x8 vf = *(const bf16x8*)(VL + crow * 64 + (((kc * 2 + lhi) ^ (crow & 7)) * 8));
          #pragma unroll
          for (int qb2 = 0; qb2 < 2; ++qb2) o[cb][qb2] = mfma32(vf, pb[qb2], o[cb][qb2]);
        }
        __builtin_amdgcn_s_setprio(0);
      }
    }
    __syncthreads();
    cur ^= 1;
  }

  #pragma unroll
  for (int cb = 0; cb < 2; ++cb)
    #pragma unroll
    for (int qb2 = 0; qb2 < 2; ++qb2) {
      const int ql = wv * 64 + qb2 * 32 + l31;
      #pragma unroll
      for (int r = 0; r < 16; ++r) {
        const int c = cb * 32 + (r & 3) + 8 * (r >> 2) + 4 * lhi;
        if (c < 48) lds.T[ql][c] = o[cb][qb2][r];
      }
      if (lhi == 0) lds.T[ql][48] = o[1][qb2][8];
    }
  __syncthreads();
  {
    const int ql = tid;
    const int qg = qt * 256 + ql;
    float vv[48];
    #pragma unroll
    for (int c = 0; c < 48; ++c) vv[c] = lds.T[ql][c];
    const float Lv = lds.T[ql][48];
    unsigned short* Ob = Opart + ((size_t)(sp * 8 + bh) * HW + qg) * 48;
    #pragma unroll
    for (int g = 0; g < 6; ++g) {
      u16x8 gg;
      #pragma unroll
      for (int j = 0; j < 8; ++j) gg[j] = f2bf(vv[g * 8 + j]);
      *(u16x8*)(Ob + g * 8) = gg;
    }
    Lpart[(size_t)(sp * 8 + bh) * HW + qg] = Lv;
  }
}

// ---------------------------------------------------------------------------
// G2: proj GEMM v2 — cooperative split-combine (384 Bf slots built once per
// block, shared via 6KB LDS) instead of 4x-duplicated per-wave combine.
// Grid (1, 256, 2) = 512 blocks, px-tile 16.
// ---------------------------------------------------------------------------
__global__ __launch_bounds__(256) void proj_gemm2_kernel(
    const unsigned short* __restrict__ Opart, const float* __restrict__ Lpart,
    const unsigned short* __restrict__ wb, float* __restrict__ Cout) {
  __shared__ __align__(16) unsigned short BfL[384 * 8];   // [kc][l4*16+l15][8], 6144 B
  const int tid = threadIdx.x;
  const int lane = tid & 63, wv = tid >> 6;
  const int l15 = lane & 15, l4 = lane >> 4;
  const int px0 = blockIdx.y * 16;
  const int b   = blockIdx.z;

  // --- cooperative Bf build: slot = kc*64 + sl4*16 + sl15 ---
  #pragma unroll
  for (int s0 = 0; s0 < 2; ++s0) {
    const int slot = s0 * 256 + tid;
    if (slot < 384) {
      const int kc = slot >> 6, q = slot & 63;
      const int sl4 = q >> 4, sl15 = q & 15;
      const int ch0 = kc * 32 + sl4 * 8;
      const int head = ch0 / 48, off = ch0 % 48;
      const int px = px0 + sl15;
      float ls = 0.f;
      #pragma unroll
      for (int sp = 0; sp < KVSPLIT; ++sp)
        ls += Lpart[(size_t)(sp * 8 + b * 4 + head) * HW + px];
      const float inv = 1.f / ls;
      float a8[8] = {};
      #pragma unroll
      for (int sp = 0; sp < KVSPLIT; ++sp) {
        const u16x8 u = *(const u16x8*)(Opart +
            ((size_t)(sp * 8 + b * 4 + head) * HW + px) * 48 + off);
        #pragma unroll
        for (int j = 0; j < 8; ++j) a8[j] += bf2f(u[j]);
      }
      u16x8 g;
      #pragma unroll
      for (int j = 0; j < 8; ++j) g[j] = f2bf(a8[j] * inv);
      *(u16x8*)&BfL[slot * 8] = g;
    }
  }
  __syncthreads();

  // --- each lane reads its 6 fragments (slot-linear -> conflict-free) ---
  bf16x8 Bf[6];
  #pragma unroll
  for (int kc = 0; kc < 6; ++kc)
    Bf[kc] = *(const bf16x8*)&BfL[(kc * 64 + l4 * 16 + l15) * 8];

  #pragma unroll
  for (int s = 0; s < 3; ++s) {
    const int oc = s * 64 + wv * 16 + l15;
    f32x4 acc = {0.f, 0.f, 0.f, 0.f};
    #pragma unroll
    for (int kc = 0; kc < 6; ++kc) {
      const bf16x8 af = *(const bf16x8*)(wb + ((size_t)kc * DIMC + oc) * 32 + l4 * 8);
      acc = mfma16(af, Bf[kc], acc);
    }
    float* Cb = Cout + ((size_t)b * DIMC + s * 64 + wv * 16) * HW + px0;
    #pragma unroll
    for (int r = 0; r < 4; ++r)
      Cb[(size_t)(l4 * 4 + r) * HW + l15] = acc[r];
  }
}

// ---------------------------------------------------------------------------
extern "C" void kernel_launch(void* const* d_in, const int* in_sizes, int n_in,
                              void* d_out, int out_size, void* d_ws, size_t ws_size,
                              hipStream_t stream) {
  const float* x      = (const float*)d_in[0];
  const float* qkv_w  = (const float*)d_in[1];
  const float* dw_w   = (const float*)d_in[2];
  const float* proj_w = (const float*)d_in[3];
  const float* temp   = (const float*)d_in[4];

  char* ws = (char*)d_ws;
  unsigned short* xb    = (unsigned short*)(ws);              //  3,145,728
  unsigned short* wqkv  = (unsigned short*)(ws + 3145728);    //    221,184
  unsigned short* wproj = (unsigned short*)(ws + 3366912);    //     73,728
  unsigned short* qkvb  = (unsigned short*)(ws + 3440640);    //  9,437,184
  unsigned short* dwb   = (unsigned short*)(ws + 12877824);   //  9,437,184
  unsigned short* Qr    = (unsigned short*)(ws + 22315008);   //  4,194,304
  unsigned short* Kr    = (unsigned short*)(ws + 26509312);   //  4,194,304
  unsigned short* Vs    = (unsigned short*)(ws + 30703616);   //  3,145,728
  unsigned short* Opart = (unsigned short*)(ws + 33849344);   // 12,582,912  [sp=4][bh][q][48]
  float*          Lpart = (float*)(ws + 46432256);            //    524,288

  // 0) pack x + weights to chunk-major bf16
  pack3_kernel<<<dim3(131), 256, 0, stream>>>(x, qkv_w, proj_w, xb, wqkv, wproj);
  // 1) qkv 1x1 conv (bf16 MFMA GEMM, bf16 out)
  qkv_gemm_kernel<<<dim3(3, 64, 2), 256, 0, stream>>>(xb, wqkv, qkvb);
  // 2) depthwise 3x3 (bf16 in/out)
  dw_conv3_kernel<<<dim3(1152), 256, 0, stream>>>(qkvb, dw_w, dwb);
  // 3) l2norm + temp*log2e + pack
  norm_pack3_kernel<<<dim3(16, 12, 2), 256, 0, stream>>>(dwb, temp, Qr, Kr, Vs);
  // 4) flash attention v8 (KVSPLIT=4, 2 blocks/CU)
  flash8_kernel<<<dim3(8, 16, KVSPLIT), 256, 0, stream>>>(Qr, Kr, Vs, temp, Opart, Lpart);
  // 5) proj GEMM v2 (cooperative combine) -> d_out (fp32)
  proj_gemm2_kernel<<<dim3(1, 256, 2), 256, 0, stream>>>(Opart, Lpart, wproj, (float*)d_out);
}